// Round 2
// baseline (228.715 us; speedup 1.0000x reference)
//
#include <hip/hip_runtime.h>
#include <cstdint>
#include <cstddef>

typedef unsigned long long ull;
typedef _Float16 f16x8 __attribute__((ext_vector_type(8)));
typedef float f32x4 __attribute__((ext_vector_type(4)));

#define N_ROWS 8192
#define SPAN   8187u   // n - k
#define MULT   1600u   // (2^32) % 8187
#define TAU_INV 10.0f
#define TOTAL_SAMP 163840u
#define INIT_KEY 0x7F800000FFFFFFFFull   // q=+inf, col=~0

// ---------------- threefry2x32 (JAX-compatible) ----------------
__device__ __forceinline__ void tf_round(unsigned &x0, unsigned &x1, int r) {
    x0 += x1; x1 = (x1 << r) | (x1 >> (32 - r)); x1 ^= x0;
}
__device__ __forceinline__ void threefry2x32(unsigned k0, unsigned k1,
                                             unsigned c0, unsigned c1,
                                             unsigned &o0, unsigned &o1) {
    unsigned ks2 = k0 ^ k1 ^ 0x1BD11BDAu;
    unsigned x0 = c0 + k0, x1 = c1 + k1;
    tf_round(x0, x1, 13); tf_round(x0, x1, 15); tf_round(x0, x1, 26); tf_round(x0, x1, 6);
    x0 += k1;  x1 += ks2 + 1u;
    tf_round(x0, x1, 17); tf_round(x0, x1, 29); tf_round(x0, x1, 16); tf_round(x0, x1, 24);
    x0 += ks2; x1 += k0 + 2u;
    tf_round(x0, x1, 13); tf_round(x0, x1, 15); tf_round(x0, x1, 26); tf_round(x0, x1, 6);
    x0 += k0;  x1 += k1 + 3u;
    tf_round(x0, x1, 17); tf_round(x0, x1, 29); tf_round(x0, x1, 16); tf_round(x0, x1, 24);
    x0 += k1;  x1 += ks2 + 4u;
    tf_round(x0, x1, 13); tf_round(x0, x1, 15); tf_round(x0, x1, 26); tf_round(x0, x1, 6);
    x0 += ks2; x1 += k0 + 5u;
    o0 = x0; o1 = x1;
}

// ---------------- async global->LDS (16B) ----------------
__device__ __forceinline__ void async16(void* lds, const void* g) {
    __builtin_amdgcn_global_load_lds((const __attribute__((address_space(1))) void*)g,
                                     (__attribute__((address_space(3))) void*)lds, 16, 0, 0);
}

// Stage 1KB chunk q (0..7) of a 64x64-f16 tile (row-major, 128 B/row), XOR-swizzled
// source chunk so LDS dest stays lane-linear. LDS slot (r,c) = global chunk c^(r&7).
__device__ __forceinline__ void stage_chunk(char* lds_tile, const char* gtile, int q, int lane) {
    int off16 = (q << 6) + lane;
    int r = off16 >> 3;
    int slot = off16 & 7;
    int csrc = slot ^ (r & 7);
    async16(lds_tile + (q << 10), gtile + r * 128 + (csrc << 4));
}

__device__ __forceinline__ f16x8 read_frag(const char* tile, int row, int c) {
    return *(const f16x8*)(tile + row * 128 + (((c ^ (row & 7)) << 4)));
}

__device__ __forceinline__ void insert5(ull* a, ull kk) {
    bool l3 = kk < a[3], l2 = kk < a[2], l1 = kk < a[1], l0 = kk < a[0];
    a[4] = l3 ? a[3] : kk;
    a[3] = l3 ? (l2 ? a[2] : kk) : a[3];
    a[2] = l2 ? (l1 ? a[1] : kk) : a[2];
    a[1] = l1 ? (l0 ? a[0] : kk) : a[1];
    a[0] = l0 ? kk : a[0];
}

__device__ __forceinline__ float wave_maxf(float v) {
#pragma unroll
    for (int o = 32; o; o >>= 1) v = fmaxf(v, __shfl_xor(v, o));
    return v;
}
__device__ __forceinline__ float wave_sumf(float v) {
#pragma unroll
    for (int o = 32; o; o >>= 1) v += __shfl_xor(v, o);
    return v;
}
__device__ __forceinline__ ull wave_minu64(ull v) {
#pragma unroll
    for (int o = 32; o; o >>= 1) {
        ull w = __shfl_xor(v, o);
        v = (w < v) ? w : v;
    }
    return v;
}

// min over the 16-lane group (lanes sharing lq => sharing rows)
__device__ __forceinline__ ull group_minu64(ull v) {
#pragma unroll
    for (int o = 8; o; o >>= 1) {
        ull w = __shfl_xor(v, o);
        v = (w < v) ? w : v;
    }
    return v;
}

// ---------------- Kernel 1: norms + f16 hi/lo split ----------------
__global__ void prep_kernel(const float* __restrict__ X,
                            float2* __restrict__ nsiv,
                            char* __restrict__ Xhi,
                            char* __restrict__ Xlo) {
    int t = blockIdx.x * 256 + threadIdx.x;
    int row = t >> 3, c = t & 7;
    const float4* src = (const float4*)(X + (size_t)row * 64 + c * 8);
    float4 a = src[0], b = src[1];
    float v[8] = {a.x, a.y, a.z, a.w, b.x, b.y, b.z, b.w};
    float ss = 0.f;
#pragma unroll
    for (int j = 0; j < 8; ++j) ss = fmaf(v[j], v[j], ss);
    ss += __shfl_xor(ss, 1);
    ss += __shfl_xor(ss, 2);
    ss += __shfl_xor(ss, 4);
    f16x8 h, l;
#pragma unroll
    for (int j = 0; j < 8; ++j) {
        _Float16 hh = (_Float16)v[j];
        h[j] = hh;
        l[j] = (_Float16)(v[j] - (float)hh);
    }
    *(f16x8*)(Xhi + (size_t)row * 128 + c * 16) = h;
    *(f16x8*)(Xlo + (size_t)row * 128 + c * 16) = l;
    if (c == 0) nsiv[row] = make_float2(ss, 1.0f / (1.0f - fminf(ss, 1.0f)));
}

// ---------------- Kernel 2: MFMA gram + fused top-5 ----------------
// grid 1024 = 128 row-tiles x 8 col-chunks (1024 cols each). 4 waves; wave w owns rows r0+16w..+15.
// 32KB LDS (A-tile reuses buf0, in-register shuffle merge) -> 4 blocks/CU = 16 waves/CU.
// Selection uses a SHARED row threshold (group-min of per-lane 5th-best): since
// min_lanes(lane-5th) >= union-5th, rejecting q >= thr_shared never drops a true
// top-5 element, and drops the insert rate ~16x -> __any() branch skips the body.
__global__ __launch_bounds__(256, 4) void gram_topk(
        const char* __restrict__ Xhi, const char* __restrict__ Xlo,
        const float2* __restrict__ nsiv, ull* __restrict__ part) {
    __shared__ __align__(16) char lds[32768];

    const int t = threadIdx.x, lane = t & 63, wv = t >> 6;
    const int lx = lane & 15, lq = lane >> 4;
    const int r0 = (blockIdx.x >> 3) * 64;
    const int ch = blockIdx.x & 7;
    const int j0base = ch * 1024;

    // ---- prologue: stage A into buf0, read frags, then recycle buf0 for B ----
    const char* gAhi = Xhi + (size_t)r0 * 128;
    const char* gAlo = Xlo + (size_t)r0 * 128;
    stage_chunk(lds,        gAhi, 2 * wv, lane);
    stage_chunk(lds,        gAhi, 2 * wv + 1, lane);
    stage_chunk(lds + 8192, gAlo, 2 * wv, lane);
    stage_chunk(lds + 8192, gAlo, 2 * wv + 1, lane);
    __syncthreads();   // A staged (vmcnt drained)

    f16x8 ahi[2], alo[2];
#pragma unroll
    for (int kc = 0; kc < 2; ++kc) {
        ahi[kc] = read_frag(lds,        wv * 16 + lx, kc * 4 + lq);
        alo[kc] = read_frag(lds + 8192, wv * 16 + lx, kc * 4 + lq);
    }
    __syncthreads();   // all waves done reading A; buf0 free

    // stage B tile 0 into buf0
    stage_chunk(lds,        Xhi + (size_t)j0base * 128, 2 * wv, lane);
    stage_chunk(lds,        Xhi + (size_t)j0base * 128, 2 * wv + 1, lane);
    stage_chunk(lds + 8192, Xlo + (size_t)j0base * 128, 2 * wv, lane);
    stage_chunk(lds + 8192, Xlo + (size_t)j0base * 128, 2 * wv + 1, lane);

    // per-lane row stats (C/D layout: row = lq*4 + reg)
    int grow[4]; float rns[4];
#pragma unroll
    for (int r = 0; r < 4; ++r) {
        grow[r] = r0 + wv * 16 + lq * 4 + r;
        rns[r] = nsiv[grow[r]].x;
    }

    ull t5[4][5];
    float thr[4];
#pragma unroll
    for (int r = 0; r < 4; ++r) {
        thr[r] = __builtin_inff();
#pragma unroll
        for (int s = 0; s < 5; ++s) t5[r][s] = INIT_KEY;
    }

    __syncthreads();   // B0 staged

    for (int it = 0; it < 16; ++it) {
        const int j0 = j0base + it * 64;
        char* cur = lds + ((it & 1) ? 16384 : 0);

        if (it + 1 < 16) {   // stage next tile into the other buffer; flies all iteration
            char* nxt = lds + ((it & 1) ? 0 : 16384);
            const char* gBh = Xhi + (size_t)(j0 + 64) * 128;
            const char* gBl = Xlo + (size_t)(j0 + 64) * 128;
            stage_chunk(nxt,        gBh, 2 * wv, lane);
            stage_chunk(nxt,        gBh, 2 * wv + 1, lane);
            stage_chunk(nxt + 8192, gBl, 2 * wv, lane);
            stage_chunk(nxt + 8192, gBl, 2 * wv + 1, lane);
        }

        float2 cn[4];
#pragma unroll
        for (int ct = 0; ct < 4; ++ct) cn[ct] = nsiv[j0 + ct * 16 + lx];

        f32x4 acc[4];
#pragma unroll
        for (int ct = 0; ct < 4; ++ct) {
            f16x8 bh0 = read_frag(cur, ct * 16 + lx, lq);
            f16x8 bh1 = read_frag(cur, ct * 16 + lx, 4 + lq);
            f16x8 bl0 = read_frag(cur + 8192, ct * 16 + lx, lq);
            f16x8 bl1 = read_frag(cur + 8192, ct * 16 + lx, 4 + lq);
            f32x4 a = {0.f, 0.f, 0.f, 0.f};
            a = __builtin_amdgcn_mfma_f32_16x16x32_f16(ahi[0], bh0, a, 0, 0, 0);
            a = __builtin_amdgcn_mfma_f32_16x16x32_f16(ahi[1], bh1, a, 0, 0, 0);
            a = __builtin_amdgcn_mfma_f32_16x16x32_f16(ahi[0], bl0, a, 0, 0, 0);
            a = __builtin_amdgcn_mfma_f32_16x16x32_f16(ahi[1], bl1, a, 0, 0, 0);
            a = __builtin_amdgcn_mfma_f32_16x16x32_f16(alo[0], bh0, a, 0, 0, 0);
            a = __builtin_amdgcn_mfma_f32_16x16x32_f16(alo[1], bh1, a, 0, 0, 0);
            acc[ct] = a;
        }

        // selection with monotone proxy q = d2 * civ_j; shared threshold + rare branch
#pragma unroll
        for (int ct = 0; ct < 4; ++ct) {
            const float civ    = cn[ct].y;
            const float cnsciv = cn[ct].x * civ;
            const float m2civ  = -2.0f * civ;
            const int   gcol   = j0 + ct * 16 + lx;
#pragma unroll
            for (int r = 0; r < 4; ++r) {
                float q = fmaf(acc[ct][r], m2civ, fmaf(rns[r], civ, cnsciv));
                if (__any(q < thr[r])) {
                    if (q < thr[r] && gcol != grow[r]) {
                        ull kk = ((ull)__float_as_uint(q) << 32) | (unsigned)gcol;
                        if (kk < t5[r][4]) insert5(t5[r], kk);
                    }
                }
            }
        }

        // tighten shared threshold for next iteration (stale-by-one is safe: monotone)
#pragma unroll
        for (int r = 0; r < 4; ++r) {
            float g = __uint_as_float((unsigned)(t5[r][4] >> 32));
            g = fminf(g, __shfl_xor(g, 1));
            g = fminf(g, __shfl_xor(g, 2));
            g = fminf(g, __shfl_xor(g, 4));
            g = fminf(g, __shfl_xor(g, 8));
            thr[r] = g;
        }

        __syncthreads();   // all waves done with cur; next buffer fully staged
    }

    // ---- in-register merge: 16 lanes x sorted-5 -> row top-5, 5 rounds of group-min ----
    // keys unique across lanes (col mod 16 == lx), so exactly the winner advances.
#pragma unroll
    for (int r = 0; r < 4; ++r) {
        ull out = ~0ull;
        ull h = t5[r][0];
#pragma unroll
        for (int s = 0; s < 5; ++s) {
            ull m = group_minu64(h);
            if (lx == s) out = m;
            bool adv = (h == m);
            if (adv) {
                t5[r][0] = t5[r][1]; t5[r][1] = t5[r][2]; t5[r][2] = t5[r][3];
                t5[r][3] = t5[r][4]; t5[r][4] = ~0ull;
                h = t5[r][0];
            }
        }
        if (lx < 5) part[(size_t)grow[r] * 40 + (size_t)ch * 5 + lx] = out;
    }
}

// ---------------- Kernel 3: finalize, 4 rows/block (wave per row), shuffle-parallel ----------------
__global__ __launch_bounds__(256) void finalize_kernel(
        const float* __restrict__ X, const float2* __restrict__ nsiv,
        const ull* __restrict__ part, float* __restrict__ rowloss) {
    const int t = threadIdx.x, lane = t & 63, wv = t >> 6;
    const int row = blockIdx.x * 4 + wv;

    // merge chunk top-5s (40 keys) -> global top-5 via 5 wave-min passes
    ull key = (lane < 40) ? part[(size_t)row * 40 + lane] : ~0ull;
    ull b[5];
#pragma unroll
    for (int s = 0; s < 5; ++s) {
        ull m = wave_minu64(key);
        b[s] = m;
        if (key == m) key = ~0ull;   // cols unique across chunks -> unique min
    }

    int pcol[5], ids[5];
#pragma unroll
    for (int s = 0; s < 5; ++s) { pcol[s] = (int)(unsigned)(b[s] & 0xFFFFFFFFull); ids[s] = pcol[s]; }
    // sort excluded ids ascending (tiny; every lane duplicates)
    for (int i = 0; i < 4; ++i)
        for (int j = 0; j < 4 - i; ++j)
            if (ids[j] > ids[j + 1]) { int tmp = ids[j]; ids[j] = ids[j + 1]; ids[j + 1] = tmp; }

    // column for this lane: lanes 0..19 = sampled negatives, 20..24 = positives
    int col = row;
    if (lane < 20) {
        unsigned m0 = (unsigned)(row * 20 + lane);
        unsigned hi, lo;
        threefry2x32(0u, 42u, m0, m0 + TOTAL_SAMP, hi, lo);
        unsigned samp = ((hi % SPAN) * MULT + (lo % SPAN)) % SPAN;
        int c = (int)samp;
#pragma unroll
        for (int s = 0; s < 5; ++s) c += (ids[s] <= c) ? 1 : 0;
        col = c;
    } else if (lane < 25) {
        col = pcol[lane - 20];
    }

    // exact fp32 Poincare distance term  -dist/tau  (diagonal -> -inf)
    float term = -INFINITY;
    if (lane < 25 && col != row) {
        const float4* xr = (const float4*)(X + (size_t)row * 64);
        const float4* xc = (const float4*)(X + (size_t)col * 64);
        float dot = 0.f;
#pragma unroll
        for (int k = 0; k < 16; ++k) {
            float4 a = xr[k];
            float4 c = xc[k];
            dot = fmaf(a.x, c.x, dot);
            dot = fmaf(a.y, c.y, dot);
            dot = fmaf(a.z, c.z, dot);
            dot = fmaf(a.w, c.w, dot);
        }
        float nsi = nsiv[row].x, nsj = nsiv[col].x;
        float d2  = fmaxf(nsi + nsj - 2.f * dot, 0.f);
        float ci  = 1.f - fminf(nsi, 1.f);
        float cj  = 1.f - fminf(nsj, 1.f);
        float den = fmaxf(ci * cj, 1e-9f);
        float z   = fmaxf(1.f + 2.f * d2 / den, 1.f);
        term = -acoshf(z) * TAU_INV;
    }

    // two masked LSEs across the wave
    float negt = (lane < 20) ? term : -INFINITY;
    float post = (lane >= 20 && lane < 25) ? term : -INFINITY;

    float nm = wave_maxf(negt);
    float ne = (lane < 20 && negt != -INFINITY) ? expf(negt - nm) : 0.f;
    float neg = nm + logf(wave_sumf(ne));

    float pm = wave_maxf(post);
    float pe = (lane >= 20 && lane < 25) ? expf(post - pm) : 0.f;
    float pos = pm + logf(wave_sumf(pe));

    if (lane == 0) rowloss[row] = neg - pos;
}

// ---------------- Kernel 4: deterministic tree sum ----------------
__global__ void reduce_kernel(const float* __restrict__ rl, float* __restrict__ out) {
    const int t = threadIdx.x;
    float s = 0.f;
#pragma unroll
    for (int i = 0; i < 32; ++i) s += rl[t + 256 * i];
#pragma unroll
    for (int o = 32; o; o >>= 1) s += __shfl_xor(s, o);
    __shared__ float ws4[4];
    if ((t & 63) == 0) ws4[t >> 6] = s;
    __syncthreads();
    if (t == 0) out[0] = (ws4[0] + ws4[1] + ws4[2] + ws4[3]) * (1.0f / 8192.0f);
}

// ---------------- launch ----------------
extern "C" void kernel_launch(void* const* d_in, const int* in_sizes, int n_in,
                              void* d_out, int out_size, void* d_ws, size_t ws_size,
                              hipStream_t stream) {
    (void)in_sizes; (void)n_in; (void)out_size; (void)ws_size;
    const float* X = (const float*)d_in[0];
    float* out = (float*)d_out;

    float2* nsiv    = (float2*)d_ws;                                  // 64 KB
    char*   Xhi     = (char*)d_ws + 65536;                            // 1 MB
    char*   Xlo     = (char*)d_ws + 65536 + 1048576;                  // 1 MB
    ull*    part    = (ull*)((char*)d_ws + 65536 + 2097152);          // 2.5 MB (8192*40*8)
    float*  rowloss = (float*)((char*)d_ws + 65536 + 2097152 + 2621440); // 32 KB

    prep_kernel<<<256, 256, 0, stream>>>(X, nsiv, Xhi, Xlo);
    gram_topk<<<1024, 256, 0, stream>>>(Xhi, Xlo, nsiv, part);
    finalize_kernel<<<2048, 256, 0, stream>>>(X, nsiv, part, rowloss);
    reduce_kernel<<<1, 256, 0, stream>>>(rowloss, out);
}

// Round 3
// 188.353 us; speedup vs baseline: 1.2143x; 1.2143x over previous
//
#include <hip/hip_runtime.h>
#include <cstdint>
#include <cstddef>

typedef unsigned long long ull;
typedef _Float16 f16x8 __attribute__((ext_vector_type(8)));
typedef float f32x4 __attribute__((ext_vector_type(4)));

#define N_ROWS 8192
#define SPAN   8187u   // n - k
#define MULT   1600u   // (2^32) % 8187
#define TAU_INV 10.0f
#define TOTAL_SAMP 163840u
#define INIT_KEY 0x7F800000FFFFFFFFull   // q=+inf, col=~0

// ---------------- threefry2x32 (JAX-compatible) ----------------
__device__ __forceinline__ void tf_round(unsigned &x0, unsigned &x1, int r) {
    x0 += x1; x1 = (x1 << r) | (x1 >> (32 - r)); x1 ^= x0;
}
__device__ __forceinline__ void threefry2x32(unsigned k0, unsigned k1,
                                             unsigned c0, unsigned c1,
                                             unsigned &o0, unsigned &o1) {
    unsigned ks2 = k0 ^ k1 ^ 0x1BD11BDAu;
    unsigned x0 = c0 + k0, x1 = c1 + k1;
    tf_round(x0, x1, 13); tf_round(x0, x1, 15); tf_round(x0, x1, 26); tf_round(x0, x1, 6);
    x0 += k1;  x1 += ks2 + 1u;
    tf_round(x0, x1, 17); tf_round(x0, x1, 29); tf_round(x0, x1, 16); tf_round(x0, x1, 24);
    x0 += ks2; x1 += k0 + 2u;
    tf_round(x0, x1, 13); tf_round(x0, x1, 15); tf_round(x0, x1, 26); tf_round(x0, x1, 6);
    x0 += k0;  x1 += k1 + 3u;
    tf_round(x0, x1, 17); tf_round(x0, x1, 29); tf_round(x0, x1, 16); tf_round(x0, x1, 24);
    x0 += k1;  x1 += ks2 + 4u;
    tf_round(x0, x1, 13); tf_round(x0, x1, 15); tf_round(x0, x1, 26); tf_round(x0, x1, 6);
    x0 += ks2; x1 += k0 + 5u;
    o0 = x0; o1 = x1;
}

// ---------------- async global->LDS (16B) ----------------
__device__ __forceinline__ void async16(void* lds, const void* g) {
    __builtin_amdgcn_global_load_lds((const __attribute__((address_space(1))) void*)g,
                                     (__attribute__((address_space(3))) void*)lds, 16, 0, 0);
}

// Stage 1KB chunk q (0..7) of a 64x64-f16 tile (row-major, 128 B/row), XOR-swizzled
// source chunk so LDS dest stays lane-linear. LDS slot (r,c) = global chunk c^(r&7).
__device__ __forceinline__ void stage_chunk(char* lds_tile, const char* gtile, int q, int lane) {
    int off16 = (q << 6) + lane;
    int r = off16 >> 3;
    int slot = off16 & 7;
    int csrc = slot ^ (r & 7);
    async16(lds_tile + (q << 10), gtile + r * 128 + (csrc << 4));
}

__device__ __forceinline__ f16x8 read_frag(const char* tile, int row, int c) {
    return *(const f16x8*)(tile + row * 128 + (((c ^ (row & 7)) << 4)));
}

__device__ __forceinline__ void insert5(ull* a, ull kk) {
    bool l3 = kk < a[3], l2 = kk < a[2], l1 = kk < a[1], l0 = kk < a[0];
    a[4] = l3 ? a[3] : kk;
    a[3] = l3 ? (l2 ? a[2] : kk) : a[3];
    a[2] = l2 ? (l1 ? a[1] : kk) : a[2];
    a[1] = l1 ? (l0 ? a[0] : kk) : a[1];
    a[0] = l0 ? kk : a[0];
}

__device__ __forceinline__ float wave_maxf(float v) {
#pragma unroll
    for (int o = 32; o; o >>= 1) v = fmaxf(v, __shfl_xor(v, o));
    return v;
}
__device__ __forceinline__ float wave_sumf(float v) {
#pragma unroll
    for (int o = 32; o; o >>= 1) v += __shfl_xor(v, o);
    return v;
}
__device__ __forceinline__ ull wave_minu64(ull v) {
#pragma unroll
    for (int o = 32; o; o >>= 1) {
        ull w = __shfl_xor(v, o);
        v = (w < v) ? w : v;
    }
    return v;
}

// min over the 16-lane group (lanes sharing lq => sharing rows)
__device__ __forceinline__ ull group_minu64(ull v) {
#pragma unroll
    for (int o = 8; o; o >>= 1) {
        ull w = __shfl_xor(v, o);
        v = (w < v) ? w : v;
    }
    return v;
}

// ---------------- Kernel 1: norms + f16 hi/lo split ----------------
__global__ void prep_kernel(const float* __restrict__ X,
                            float2* __restrict__ nsiv,
                            char* __restrict__ Xhi,
                            char* __restrict__ Xlo) {
    int t = blockIdx.x * 256 + threadIdx.x;
    int row = t >> 3, c = t & 7;
    const float4* src = (const float4*)(X + (size_t)row * 64 + c * 8);
    float4 a = src[0], b = src[1];
    float v[8] = {a.x, a.y, a.z, a.w, b.x, b.y, b.z, b.w};
    float ss = 0.f;
#pragma unroll
    for (int j = 0; j < 8; ++j) ss = fmaf(v[j], v[j], ss);
    ss += __shfl_xor(ss, 1);
    ss += __shfl_xor(ss, 2);
    ss += __shfl_xor(ss, 4);
    f16x8 h, l;
#pragma unroll
    for (int j = 0; j < 8; ++j) {
        _Float16 hh = (_Float16)v[j];
        h[j] = hh;
        l[j] = (_Float16)(v[j] - (float)hh);
    }
    *(f16x8*)(Xhi + (size_t)row * 128 + c * 16) = h;
    *(f16x8*)(Xlo + (size_t)row * 128 + c * 16) = l;
    if (c == 0) nsiv[row] = make_float2(ss, 1.0f / (1.0f - fminf(ss, 1.0f)));
}

// ---------------- Kernel 2: MFMA gram + fused top-5 ----------------
// grid 1024 = 128 row-tiles x 8 col-chunks (1024 cols each). 4 waves; wave w owns rows r0+16w..+15.
// 32KB LDS (A-tile reuses buf0, in-register shuffle merge).
// __launch_bounds__(256,3): the (256,4) variant made the compiler target the
// 64-VGPR bucket and spill t5[] to scratch (FETCH 8.6->121 MB, WRITE 4->42 MB).
// (256,3) is the proven 84-VGPR no-spill bucket; LDS 32KB still allows 4+ blocks/CU.
__global__ __launch_bounds__(256, 3) void gram_topk(
        const char* __restrict__ Xhi, const char* __restrict__ Xlo,
        const float2* __restrict__ nsiv, ull* __restrict__ part) {
    __shared__ __align__(16) char lds[32768];

    const int t = threadIdx.x, lane = t & 63, wv = t >> 6;
    const int lx = lane & 15, lq = lane >> 4;
    const int r0 = (blockIdx.x >> 3) * 64;
    const int ch = blockIdx.x & 7;
    const int j0base = ch * 1024;

    // ---- prologue: stage A into buf0, read frags, then recycle buf0 for B ----
    const char* gAhi = Xhi + (size_t)r0 * 128;
    const char* gAlo = Xlo + (size_t)r0 * 128;
    stage_chunk(lds,        gAhi, 2 * wv, lane);
    stage_chunk(lds,        gAhi, 2 * wv + 1, lane);
    stage_chunk(lds + 8192, gAlo, 2 * wv, lane);
    stage_chunk(lds + 8192, gAlo, 2 * wv + 1, lane);
    __syncthreads();   // A staged (vmcnt drained)

    f16x8 ahi[2], alo[2];
#pragma unroll
    for (int kc = 0; kc < 2; ++kc) {
        ahi[kc] = read_frag(lds,        wv * 16 + lx, kc * 4 + lq);
        alo[kc] = read_frag(lds + 8192, wv * 16 + lx, kc * 4 + lq);
    }
    __syncthreads();   // all waves done reading A; buf0 free

    // stage B tile 0 into buf0
    stage_chunk(lds,        Xhi + (size_t)j0base * 128, 2 * wv, lane);
    stage_chunk(lds,        Xhi + (size_t)j0base * 128, 2 * wv + 1, lane);
    stage_chunk(lds + 8192, Xlo + (size_t)j0base * 128, 2 * wv, lane);
    stage_chunk(lds + 8192, Xlo + (size_t)j0base * 128, 2 * wv + 1, lane);

    // per-lane row stats (C/D layout: row = lq*4 + reg)
    int grow[4]; float rns[4];
#pragma unroll
    for (int r = 0; r < 4; ++r) {
        grow[r] = r0 + wv * 16 + lq * 4 + r;
        rns[r] = nsiv[grow[r]].x;
    }

    ull t5[4][5];
    float thr[4];
#pragma unroll
    for (int r = 0; r < 4; ++r) {
        thr[r] = __builtin_inff();
#pragma unroll
        for (int s = 0; s < 5; ++s) t5[r][s] = INIT_KEY;
    }

    __syncthreads();   // B0 staged

    for (int it = 0; it < 16; ++it) {
        const int j0 = j0base + it * 64;
        char* cur = lds + ((it & 1) ? 16384 : 0);

        if (it + 1 < 16) {   // stage next tile into the other buffer; flies all iteration
            char* nxt = lds + ((it & 1) ? 0 : 16384);
            const char* gBh = Xhi + (size_t)(j0 + 64) * 128;
            const char* gBl = Xlo + (size_t)(j0 + 64) * 128;
            stage_chunk(nxt,        gBh, 2 * wv, lane);
            stage_chunk(nxt,        gBh, 2 * wv + 1, lane);
            stage_chunk(nxt + 8192, gBl, 2 * wv, lane);
            stage_chunk(nxt + 8192, gBl, 2 * wv + 1, lane);
        }

        float2 cn[4];
#pragma unroll
        for (int ct = 0; ct < 4; ++ct) cn[ct] = nsiv[j0 + ct * 16 + lx];

        f32x4 acc[4];
#pragma unroll
        for (int ct = 0; ct < 4; ++ct) {
            f16x8 bh0 = read_frag(cur, ct * 16 + lx, lq);
            f16x8 bh1 = read_frag(cur, ct * 16 + lx, 4 + lq);
            f16x8 bl0 = read_frag(cur + 8192, ct * 16 + lx, lq);
            f16x8 bl1 = read_frag(cur + 8192, ct * 16 + lx, 4 + lq);
            f32x4 a = {0.f, 0.f, 0.f, 0.f};
            a = __builtin_amdgcn_mfma_f32_16x16x32_f16(ahi[0], bh0, a, 0, 0, 0);
            a = __builtin_amdgcn_mfma_f32_16x16x32_f16(ahi[1], bh1, a, 0, 0, 0);
            a = __builtin_amdgcn_mfma_f32_16x16x32_f16(ahi[0], bl0, a, 0, 0, 0);
            a = __builtin_amdgcn_mfma_f32_16x16x32_f16(ahi[1], bl1, a, 0, 0, 0);
            a = __builtin_amdgcn_mfma_f32_16x16x32_f16(alo[0], bh0, a, 0, 0, 0);
            a = __builtin_amdgcn_mfma_f32_16x16x32_f16(alo[1], bh1, a, 0, 0, 0);
            acc[ct] = a;
        }

        // selection with monotone proxy q = d2 * civ_j; shared threshold + rare branch
#pragma unroll
        for (int ct = 0; ct < 4; ++ct) {
            const float civ    = cn[ct].y;
            const float cnsciv = cn[ct].x * civ;
            const float m2civ  = -2.0f * civ;
            const int   gcol   = j0 + ct * 16 + lx;
#pragma unroll
            for (int r = 0; r < 4; ++r) {
                float q = fmaf(acc[ct][r], m2civ, fmaf(rns[r], civ, cnsciv));
                if (__any(q < thr[r])) {
                    if (q < thr[r] && gcol != grow[r]) {
                        ull kk = ((ull)__float_as_uint(q) << 32) | (unsigned)gcol;
                        if (kk < t5[r][4]) insert5(t5[r], kk);
                    }
                }
            }
        }

        // tighten shared threshold for next iteration (stale-by-one is safe: monotone)
#pragma unroll
        for (int r = 0; r < 4; ++r) {
            float g = __uint_as_float((unsigned)(t5[r][4] >> 32));
            g = fminf(g, __shfl_xor(g, 1));
            g = fminf(g, __shfl_xor(g, 2));
            g = fminf(g, __shfl_xor(g, 4));
            g = fminf(g, __shfl_xor(g, 8));
            thr[r] = g;
        }

        __syncthreads();   // all waves done with cur; next buffer fully staged
    }

    // ---- in-register merge: 16 lanes x sorted-5 -> row top-5, 5 rounds of group-min ----
    // keys unique across lanes (col mod 16 == lx), so exactly the winner advances.
#pragma unroll
    for (int r = 0; r < 4; ++r) {
        ull out = ~0ull;
        ull h = t5[r][0];
#pragma unroll
        for (int s = 0; s < 5; ++s) {
            ull m = group_minu64(h);
            if (lx == s) out = m;
            bool adv = (h == m);
            if (adv) {
                t5[r][0] = t5[r][1]; t5[r][1] = t5[r][2]; t5[r][2] = t5[r][3];
                t5[r][3] = t5[r][4]; t5[r][4] = ~0ull;
                h = t5[r][0];
            }
        }
        if (lx < 5) part[(size_t)grow[r] * 40 + (size_t)ch * 5 + lx] = out;
    }
}

// ---------------- Kernel 3: finalize, 4 rows/block (wave per row), shuffle-parallel ----------------
__global__ __launch_bounds__(256) void finalize_kernel(
        const float* __restrict__ X, const float2* __restrict__ nsiv,
        const ull* __restrict__ part, float* __restrict__ rowloss) {
    const int t = threadIdx.x, lane = t & 63, wv = t >> 6;
    const int row = blockIdx.x * 4 + wv;

    // merge chunk top-5s (40 keys) -> global top-5 via 5 wave-min passes
    ull key = (lane < 40) ? part[(size_t)row * 40 + lane] : ~0ull;
    ull b[5];
#pragma unroll
    for (int s = 0; s < 5; ++s) {
        ull m = wave_minu64(key);
        b[s] = m;
        if (key == m) key = ~0ull;   // cols unique across chunks -> unique min
    }

    int pcol[5], ids[5];
#pragma unroll
    for (int s = 0; s < 5; ++s) { pcol[s] = (int)(unsigned)(b[s] & 0xFFFFFFFFull); ids[s] = pcol[s]; }
    // sort excluded ids ascending (tiny; every lane duplicates)
    for (int i = 0; i < 4; ++i)
        for (int j = 0; j < 4 - i; ++j)
            if (ids[j] > ids[j + 1]) { int tmp = ids[j]; ids[j] = ids[j + 1]; ids[j + 1] = tmp; }

    // column for this lane: lanes 0..19 = sampled negatives, 20..24 = positives
    int col = row;
    if (lane < 20) {
        unsigned m0 = (unsigned)(row * 20 + lane);
        unsigned hi, lo;
        threefry2x32(0u, 42u, m0, m0 + TOTAL_SAMP, hi, lo);
        unsigned samp = ((hi % SPAN) * MULT + (lo % SPAN)) % SPAN;
        int c = (int)samp;
#pragma unroll
        for (int s = 0; s < 5; ++s) c += (ids[s] <= c) ? 1 : 0;
        col = c;
    } else if (lane < 25) {
        col = pcol[lane - 20];
    }

    // exact fp32 Poincare distance term  -dist/tau  (diagonal -> -inf)
    float term = -INFINITY;
    if (lane < 25 && col != row) {
        const float4* xr = (const float4*)(X + (size_t)row * 64);
        const float4* xc = (const float4*)(X + (size_t)col * 64);
        float dot = 0.f;
#pragma unroll
        for (int k = 0; k < 16; ++k) {
            float4 a = xr[k];
            float4 c = xc[k];
            dot = fmaf(a.x, c.x, dot);
            dot = fmaf(a.y, c.y, dot);
            dot = fmaf(a.z, c.z, dot);
            dot = fmaf(a.w, c.w, dot);
        }
        float nsi = nsiv[row].x, nsj = nsiv[col].x;
        float d2  = fmaxf(nsi + nsj - 2.f * dot, 0.f);
        float ci  = 1.f - fminf(nsi, 1.f);
        float cj  = 1.f - fminf(nsj, 1.f);
        float den = fmaxf(ci * cj, 1e-9f);
        float z   = fmaxf(1.f + 2.f * d2 / den, 1.f);
        term = -acoshf(z) * TAU_INV;
    }

    // two masked LSEs across the wave
    float negt = (lane < 20) ? term : -INFINITY;
    float post = (lane >= 20 && lane < 25) ? term : -INFINITY;

    float nm = wave_maxf(negt);
    float ne = (lane < 20 && negt != -INFINITY) ? expf(negt - nm) : 0.f;
    float neg = nm + logf(wave_sumf(ne));

    float pm = wave_maxf(post);
    float pe = (lane >= 20 && lane < 25) ? expf(post - pm) : 0.f;
    float pos = pm + logf(wave_sumf(pe));

    if (lane == 0) rowloss[row] = neg - pos;
}

// ---------------- Kernel 4: deterministic tree sum ----------------
__global__ void reduce_kernel(const float* __restrict__ rl, float* __restrict__ out) {
    const int t = threadIdx.x;
    float s = 0.f;
#pragma unroll
    for (int i = 0; i < 32; ++i) s += rl[t + 256 * i];
#pragma unroll
    for (int o = 32; o; o >>= 1) s += __shfl_xor(s, o);
    __shared__ float ws4[4];
    if ((t & 63) == 0) ws4[t >> 6] = s;
    __syncthreads();
    if (t == 0) out[0] = (ws4[0] + ws4[1] + ws4[2] + ws4[3]) * (1.0f / 8192.0f);
}

// ---------------- launch ----------------
extern "C" void kernel_launch(void* const* d_in, const int* in_sizes, int n_in,
                              void* d_out, int out_size, void* d_ws, size_t ws_size,
                              hipStream_t stream) {
    (void)in_sizes; (void)n_in; (void)out_size; (void)ws_size;
    const float* X = (const float*)d_in[0];
    float* out = (float*)d_out;

    float2* nsiv    = (float2*)d_ws;                                  // 64 KB
    char*   Xhi     = (char*)d_ws + 65536;                            // 1 MB
    char*   Xlo     = (char*)d_ws + 65536 + 1048576;                  // 1 MB
    ull*    part    = (ull*)((char*)d_ws + 65536 + 2097152);          // 2.5 MB (8192*40*8)
    float*  rowloss = (float*)((char*)d_ws + 65536 + 2097152 + 2621440); // 32 KB

    prep_kernel<<<256, 256, 0, stream>>>(X, nsiv, Xhi, Xlo);
    gram_topk<<<1024, 256, 0, stream>>>(Xhi, Xlo, nsiv, part);
    finalize_kernel<<<2048, 256, 0, stream>>>(X, nsiv, part, rowloss);
    reduce_kernel<<<1, 256, 0, stream>>>(rowloss, out);
}

// Round 5
// 157.454 us; speedup vs baseline: 1.4526x; 1.1962x over previous
//
#include <hip/hip_runtime.h>
#include <cstdint>
#include <cstddef>

typedef unsigned long long ull;
typedef _Float16 f16x8 __attribute__((ext_vector_type(8)));
typedef float f32x4 __attribute__((ext_vector_type(4)));

#define N_ROWS 8192
#define SPAN   8187u   // n - k
#define MULT   1600u   // (2^32) % 8187
#define TAU_INV 10.0f
#define TOTAL_SAMP 163840u

// ---------------- threefry2x32 (JAX-compatible) ----------------
__device__ __forceinline__ void tf_round(unsigned &x0, unsigned &x1, int r) {
    x0 += x1; x1 = (x1 << r) | (x1 >> (32 - r)); x1 ^= x0;
}
__device__ __forceinline__ void threefry2x32(unsigned k0, unsigned k1,
                                             unsigned c0, unsigned c1,
                                             unsigned &o0, unsigned &o1) {
    unsigned ks2 = k0 ^ k1 ^ 0x1BD11BDAu;
    unsigned x0 = c0 + k0, x1 = c1 + k1;
    tf_round(x0, x1, 13); tf_round(x0, x1, 15); tf_round(x0, x1, 26); tf_round(x0, x1, 6);
    x0 += k1;  x1 += ks2 + 1u;
    tf_round(x0, x1, 17); tf_round(x0, x1, 29); tf_round(x0, x1, 16); tf_round(x0, x1, 24);
    x0 += ks2; x1 += k0 + 2u;
    tf_round(x0, x1, 13); tf_round(x0, x1, 15); tf_round(x0, x1, 26); tf_round(x0, x1, 6);
    x0 += k0;  x1 += k1 + 3u;
    tf_round(x0, x1, 17); tf_round(x0, x1, 29); tf_round(x0, x1, 16); tf_round(x0, x1, 24);
    x0 += k1;  x1 += ks2 + 4u;
    tf_round(x0, x1, 13); tf_round(x0, x1, 15); tf_round(x0, x1, 26); tf_round(x0, x1, 6);
    x0 += ks2; x1 += k0 + 5u;
    o0 = x0; o1 = x1;
}

// ---------------- async global->LDS (16B), offset folded into pointers ----------------
// NOTE (round-4 lesson): do NOT use the builtin's 4th (imm offset) arg — semantics
// unverified on gfx950 (LDS-vs-global ambiguity caused a correctness failure).
__device__ __forceinline__ void async16(void* lds, const void* g) {
    __builtin_amdgcn_global_load_lds((const __attribute__((address_space(1))) void*)g,
                                     (__attribute__((address_space(3))) void*)lds, 16, 0, 0);
}

// Stage 1KB chunk q (0..7) of a 64x64-f16 tile (row-major, 128 B/row), XOR-swizzled
// source chunk so LDS dest stays lane-linear. LDS slot (r,c) = global chunk c^(r&7).
__device__ __forceinline__ void stage_chunk(char* lds_tile, const char* gtile, int q, int lane) {
    int off16 = (q << 6) + lane;
    int r = off16 >> 3;
    int slot = off16 & 7;
    int csrc = slot ^ (r & 7);
    async16(lds_tile + (q << 10), gtile + r * 128 + (csrc << 4));
}

__device__ __forceinline__ f16x8 read_frag(const char* tile, int row, int c) {
    return *(const f16x8*)(tile + row * 128 + (((c ^ (row & 7)) << 4)));
}

__device__ __forceinline__ float wave_maxf(float v) {
#pragma unroll
    for (int o = 32; o; o >>= 1) v = fmaxf(v, __shfl_xor(v, o));
    return v;
}
__device__ __forceinline__ float wave_sumf(float v) {
#pragma unroll
    for (int o = 32; o; o >>= 1) v += __shfl_xor(v, o);
    return v;
}
__device__ __forceinline__ ull wave_minu64(ull v) {
#pragma unroll
    for (int o = 32; o; o >>= 1) {
        ull w = __shfl_xor(v, o);
        v = (w < v) ? w : v;
    }
    return v;
}

// min over the 16-lane group (lanes sharing lq => sharing rows)
__device__ __forceinline__ ull group_minu64(ull v) {
#pragma unroll
    for (int o = 8; o; o >>= 1) {
        ull w = __shfl_xor(v, o);
        v = (w < v) ? w : v;
    }
    return v;
}

// ---------------- Kernel 1: norms + f16 hi/lo split ----------------
__global__ void prep_kernel(const float* __restrict__ X,
                            float2* __restrict__ nsiv,
                            char* __restrict__ Xhi,
                            char* __restrict__ Xlo) {
    int t = blockIdx.x * 256 + threadIdx.x;
    int row = t >> 3, c = t & 7;
    const float4* src = (const float4*)(X + (size_t)row * 64 + c * 8);
    float4 a = src[0], b = src[1];
    float v[8] = {a.x, a.y, a.z, a.w, b.x, b.y, b.z, b.w};
    float ss = 0.f;
#pragma unroll
    for (int j = 0; j < 8; ++j) ss = fmaf(v[j], v[j], ss);
    ss += __shfl_xor(ss, 1);
    ss += __shfl_xor(ss, 2);
    ss += __shfl_xor(ss, 4);
    f16x8 h, l;
#pragma unroll
    for (int j = 0; j < 8; ++j) {
        _Float16 hh = (_Float16)v[j];
        h[j] = hh;
        l[j] = (_Float16)(v[j] - (float)hh);
    }
    *(f16x8*)(Xhi + (size_t)row * 128 + c * 16) = h;
    *(f16x8*)(Xlo + (size_t)row * 128 + c * 16) = l;
    if (c == 0) nsiv[row] = make_float2(ss, 1.0f / (1.0f - fminf(ss, 1.0f)));
}

// ---------------- Kernel 2: MFMA gram + fused top-5 ----------------
// grid 1024 = 128 row-tiles x 8 col-chunks. 4 waves; wave w owns rows r0+16w..+15.
// v5: branchless f32/u32 insert + hoisted addressing (v4), staging via offset-0
// async16 with offsets folded into pointers (v3-identical staging instructions).
__global__ __launch_bounds__(256, 3) void gram_topk(
        const char* __restrict__ Xhi, const char* __restrict__ Xlo,
        const float2* __restrict__ nsiv, ull* __restrict__ part) {
    __shared__ __align__(16) char lds[32768];

    const int t = threadIdx.x, lane = t & 63, wv = t >> 6;
    const int lx = lane & 15, lq = lane >> 4;
    const int r0 = (blockIdx.x >> 3) * 64;
    const int ch = blockIdx.x & 7;
    const int j0base = ch * 1024;

    // ---- prologue: stage A into buf0, read frags, then recycle buf0 for B ----
    const char* gAhi = Xhi + (size_t)r0 * 128;
    const char* gAlo = Xlo + (size_t)r0 * 128;
    stage_chunk(lds,        gAhi, 2 * wv, lane);
    stage_chunk(lds,        gAhi, 2 * wv + 1, lane);
    stage_chunk(lds + 8192, gAlo, 2 * wv, lane);
    stage_chunk(lds + 8192, gAlo, 2 * wv + 1, lane);
    __syncthreads();   // A staged (vmcnt drained)

    f16x8 ahi[2], alo[2];
#pragma unroll
    for (int kc = 0; kc < 2; ++kc) {
        ahi[kc] = read_frag(lds,        wv * 16 + lx, kc * 4 + lq);
        alo[kc] = read_frag(lds + 8192, wv * 16 + lx, kc * 4 + lq);
    }
    __syncthreads();   // all waves done reading A; buf0 free

    // stage B tile 0 into buf0
    stage_chunk(lds,        Xhi + (size_t)j0base * 128, 2 * wv, lane);
    stage_chunk(lds,        Xhi + (size_t)j0base * 128, 2 * wv + 1, lane);
    stage_chunk(lds + 8192, Xlo + (size_t)j0base * 128, 2 * wv, lane);
    stage_chunk(lds + 8192, Xlo + (size_t)j0base * 128, 2 * wv + 1, lane);

    // ---- precomputed addresses (lane-constant) ----
    // B-frag LDS reads: row = ct*16+lx, so row&7 == lx&7 -> xor term lane-const.
    const char* pB0 = lds + lx * 128 + ((lq       ^ (lx & 7)) << 4);
    const char* pB1 = lds + lx * 128 + (((4 + lq) ^ (lx & 7)) << 4);
    // staging source pointers (swizzled per-lane offset); +1024 sibling = rows +8
    const int rA  = 16 * wv + (lane >> 3);
    const int csA = (lane & 7) ^ ((lane >> 3) & 7);
    const char* gbh = Xhi + (size_t)(j0base + 64) * 128 + rA * 128 + (csA << 4);
    const char* gbl = Xlo + (size_t)(j0base + 64) * 128 + rA * 128 + (csA << 4);
    const float2* pn = nsiv + j0base + lx;
    const int jlx = j0base + lx;

    // per-lane row stats (C/D layout: row = lq*4 + reg)
    int grow_m[4]; float rns[4];
#pragma unroll
    for (int r = 0; r < 4; ++r) {
        int gr = r0 + wv * 16 + lq * 4 + r;
        grow_m[r] = gr - jlx;          // diag when itofs + ct*16 == grow_m[r]
        rns[r] = nsiv[gr].x;
    }

    float tk[4][5]; unsigned tc[4][5]; float thr[4];
#pragma unroll
    for (int r = 0; r < 4; ++r) {
        thr[r] = __builtin_inff();
#pragma unroll
        for (int s = 0; s < 5; ++s) { tk[r][s] = __builtin_inff(); tc[r][s] = 0xFFFFFFFFu; }
    }

    int itofs = 0;
    __syncthreads();   // B0 staged

#define ITER(SEL, NSEL, DO_STAGE) do {                                        \
    if (DO_STAGE) {                                                           \
        async16(lds + (NSEL) + wv * 2048,               gbh);                 \
        async16(lds + (NSEL) + wv * 2048 + 1024,        gbh + 1024);          \
        async16(lds + (NSEL) + 8192 + wv * 2048,        gbl);                 \
        async16(lds + (NSEL) + 8192 + wv * 2048 + 1024, gbl + 1024);          \
        gbh += 8192; gbl += 8192;                                             \
    }                                                                         \
    float2 cnv[4] = {pn[0], pn[16], pn[32], pn[48]};                          \
    pn += 64;                                                                 \
    f32x4 acc[4];                                                             \
    _Pragma("unroll")                                                         \
    for (int ct = 0; ct < 4; ++ct) {                                          \
        const f16x8 bh0 = *(const f16x8*)(pB0 + (SEL) + ct * 2048);           \
        const f16x8 bh1 = *(const f16x8*)(pB1 + (SEL) + ct * 2048);           \
        const f16x8 bl0 = *(const f16x8*)(pB0 + (SEL) + 8192 + ct * 2048);    \
        const f16x8 bl1 = *(const f16x8*)(pB1 + (SEL) + 8192 + ct * 2048);    \
        f32x4 a = {0.f, 0.f, 0.f, 0.f};                                       \
        a = __builtin_amdgcn_mfma_f32_16x16x32_f16(ahi[0], bh0, a, 0, 0, 0);  \
        a = __builtin_amdgcn_mfma_f32_16x16x32_f16(ahi[1], bh1, a, 0, 0, 0);  \
        a = __builtin_amdgcn_mfma_f32_16x16x32_f16(ahi[0], bl0, a, 0, 0, 0);  \
        a = __builtin_amdgcn_mfma_f32_16x16x32_f16(ahi[1], bl1, a, 0, 0, 0);  \
        a = __builtin_amdgcn_mfma_f32_16x16x32_f16(alo[0], bh0, a, 0, 0, 0);  \
        a = __builtin_amdgcn_mfma_f32_16x16x32_f16(alo[1], bh1, a, 0, 0, 0);  \
        acc[ct] = a;                                                          \
    }                                                                         \
    _Pragma("unroll")                                                         \
    for (int ct = 0; ct < 4; ++ct) {                                          \
        const float civ    = cnv[ct].y;                                       \
        const float cnsciv = cnv[ct].x * civ;                                 \
        const float m2civ  = -2.0f * civ;                                     \
        const int   gcol   = jlx + itofs + ct * 16;                           \
        _Pragma("unroll")                                                     \
        for (int r = 0; r < 4; ++r) {                                         \
            float q = fmaf(acc[ct][r], m2civ, fmaf(rns[r], civ, cnsciv));     \
            q = (grow_m[r] == itofs + ct * 16) ? __builtin_inff() : q;        \
            if (__any(q < thr[r])) {                                          \
                bool b0 = q < tk[r][0], b1 = q < tk[r][1], b2 = q < tk[r][2]; \
                bool b3 = q < tk[r][3], b4 = q < tk[r][4];                    \
                tk[r][4] = b3 ? tk[r][3] : (b4 ? q : tk[r][4]);               \
                tc[r][4] = b3 ? tc[r][3] : (b4 ? (unsigned)gcol : tc[r][4]);  \
                tk[r][3] = b2 ? tk[r][2] : (b3 ? q : tk[r][3]);               \
                tc[r][3] = b2 ? tc[r][2] : (b3 ? (unsigned)gcol : tc[r][3]);  \
                tk[r][2] = b1 ? tk[r][1] : (b2 ? q : tk[r][2]);               \
                tc[r][2] = b1 ? tc[r][1] : (b2 ? (unsigned)gcol : tc[r][2]);  \
                tk[r][1] = b0 ? tk[r][0] : (b1 ? q : tk[r][1]);               \
                tc[r][1] = b0 ? tc[r][0] : (b1 ? (unsigned)gcol : tc[r][1]);  \
                tk[r][0] = b0 ? q : tk[r][0];                                 \
                tc[r][0] = b0 ? (unsigned)gcol : tc[r][0];                    \
            }                                                                 \
        }                                                                     \
    }                                                                         \
    _Pragma("unroll")                                                         \
    for (int r = 0; r < 4; ++r) {                                             \
        float g = tk[r][4];                                                   \
        g = fminf(g, __shfl_xor(g, 1));                                       \
        g = fminf(g, __shfl_xor(g, 2));                                       \
        g = fminf(g, __shfl_xor(g, 4));                                       \
        g = fminf(g, __shfl_xor(g, 8));                                       \
        thr[r] = g;                                                           \
    }                                                                         \
    itofs += 64;                                                              \
    __syncthreads();                                                          \
} while (0)

#pragma unroll 1
    for (int ip = 0; ip < 8; ++ip) {
        ITER(0, 16384, true);       // it = 2*ip   : read buf0, stage buf1
        ITER(16384, 0, ip < 7);     // it = 2*ip+1 : read buf1, stage buf0
    }
#undef ITER

    // ---- pack + in-register merge: 16 lanes x sorted-5 -> row top-5 ----
    // keys unique across lanes (col mod 16 == lx), so exactly the winner advances.
#pragma unroll
    for (int r = 0; r < 4; ++r) {
        ull t5r[5];
#pragma unroll
        for (int s = 0; s < 5; ++s)
            t5r[s] = ((ull)(unsigned)__float_as_uint(tk[r][s]) << 32) | (ull)tc[r][s];
        ull out = ~0ull;
        ull h = t5r[0];
#pragma unroll
        for (int s = 0; s < 5; ++s) {
            ull m = group_minu64(h);
            if (lx == s) out = m;
            if (h == m) {
                t5r[0] = t5r[1]; t5r[1] = t5r[2]; t5r[2] = t5r[3];
                t5r[3] = t5r[4]; t5r[4] = ~0ull;
                h = t5r[0];
            }
        }
        if (lx < 5) part[(size_t)(grow_m[r] + jlx) * 40 + (size_t)ch * 5 + lx] = out;
    }
}

// ---------------- Kernel 3: finalize, 4 rows/block (wave per row), shuffle-parallel ----------------
__global__ __launch_bounds__(256) void finalize_kernel(
        const float* __restrict__ X, const float2* __restrict__ nsiv,
        const ull* __restrict__ part, float* __restrict__ rowloss) {
    const int t = threadIdx.x, lane = t & 63, wv = t >> 6;
    const int row = blockIdx.x * 4 + wv;

    // merge chunk top-5s (40 keys) -> global top-5 via 5 wave-min passes
    ull key = (lane < 40) ? part[(size_t)row * 40 + lane] : ~0ull;
    ull b[5];
#pragma unroll
    for (int s = 0; s < 5; ++s) {
        ull m = wave_minu64(key);
        b[s] = m;
        if (key == m) key = ~0ull;   // cols unique across chunks -> unique min
    }

    int pcol[5], ids[5];
#pragma unroll
    for (int s = 0; s < 5; ++s) { pcol[s] = (int)(unsigned)(b[s] & 0xFFFFFFFFull); ids[s] = pcol[s]; }
    // sort excluded ids ascending (tiny; every lane duplicates)
    for (int i = 0; i < 4; ++i)
        for (int j = 0; j < 4 - i; ++j)
            if (ids[j] > ids[j + 1]) { int tmp = ids[j]; ids[j] = ids[j + 1]; ids[j + 1] = tmp; }

    // column for this lane: lanes 0..19 = sampled negatives, 20..24 = positives
    int col = row;
    if (lane < 20) {
        unsigned m0 = (unsigned)(row * 20 + lane);
        unsigned hi, lo;
        threefry2x32(0u, 42u, m0, m0 + TOTAL_SAMP, hi, lo);
        unsigned samp = ((hi % SPAN) * MULT + (lo % SPAN)) % SPAN;
        int c = (int)samp;
#pragma unroll
        for (int s = 0; s < 5; ++s) c += (ids[s] <= c) ? 1 : 0;
        col = c;
    } else if (lane < 25) {
        col = pcol[lane - 20];
    }

    // exact fp32 Poincare distance term  -dist/tau  (diagonal -> -inf)
    float term = -INFINITY;
    if (lane < 25 && col != row) {
        const float4* xr = (const float4*)(X + (size_t)row * 64);
        const float4* xc = (const float4*)(X + (size_t)col * 64);
        float dot = 0.f;
#pragma unroll
        for (int k = 0; k < 16; ++k) {
            float4 a = xr[k];
            float4 c = xc[k];
            dot = fmaf(a.x, c.x, dot);
            dot = fmaf(a.y, c.y, dot);
            dot = fmaf(a.z, c.z, dot);
            dot = fmaf(a.w, c.w, dot);
        }
        float nsi = nsiv[row].x, nsj = nsiv[col].x;
        float d2  = fmaxf(nsi + nsj - 2.f * dot, 0.f);
        float ci  = 1.f - fminf(nsi, 1.f);
        float cj  = 1.f - fminf(nsj, 1.f);
        float den = fmaxf(ci * cj, 1e-9f);
        float z   = fmaxf(1.f + 2.f * d2 / den, 1.f);
        term = -acoshf(z) * TAU_INV;
    }

    // two masked LSEs across the wave
    float negt = (lane < 20) ? term : -INFINITY;
    float post = (lane >= 20 && lane < 25) ? term : -INFINITY;

    float nm = wave_maxf(negt);
    float ne = (lane < 20 && negt != -INFINITY) ? expf(negt - nm) : 0.f;
    float neg = nm + logf(wave_sumf(ne));

    float pm = wave_maxf(post);
    float pe = (lane >= 20 && lane < 25) ? expf(post - pm) : 0.f;
    float pos = pm + logf(wave_sumf(pe));

    if (lane == 0) rowloss[row] = neg - pos;
}

// ---------------- Kernel 4: deterministic tree sum ----------------
__global__ void reduce_kernel(const float* __restrict__ rl, float* __restrict__ out) {
    const int t = threadIdx.x;
    float s = 0.f;
#pragma unroll
    for (int i = 0; i < 32; ++i) s += rl[t + 256 * i];
#pragma unroll
    for (int o = 32; o; o >>= 1) s += __shfl_xor(s, o);
    __shared__ float ws4[4];
    if ((t & 63) == 0) ws4[t >> 6] = s;
    __syncthreads();
    if (t == 0) out[0] = (ws4[0] + ws4[1] + ws4[2] + ws4[3]) * (1.0f / 8192.0f);
}

// ---------------- launch ----------------
extern "C" void kernel_launch(void* const* d_in, const int* in_sizes, int n_in,
                              void* d_out, int out_size, void* d_ws, size_t ws_size,
                              hipStream_t stream) {
    (void)in_sizes; (void)n_in; (void)out_size; (void)ws_size;
    const float* X = (const float*)d_in[0];
    float* out = (float*)d_out;

    float2* nsiv    = (float2*)d_ws;                                  // 64 KB
    char*   Xhi     = (char*)d_ws + 65536;                            // 1 MB
    char*   Xlo     = (char*)d_ws + 65536 + 1048576;                  // 1 MB
    ull*    part    = (ull*)((char*)d_ws + 65536 + 2097152);          // 2.5 MB (8192*40*8)
    float*  rowloss = (float*)((char*)d_ws + 65536 + 2097152 + 2621440); // 32 KB

    prep_kernel<<<256, 256, 0, stream>>>(X, nsiv, Xhi, Xlo);
    gram_topk<<<1024, 256, 0, stream>>>(Xhi, Xlo, nsiv, part);
    finalize_kernel<<<2048, 256, 0, stream>>>(X, nsiv, part, rowloss);
    reduce_kernel<<<1, 256, 0, stream>>>(rowloss, out);
}

// Round 6
// 117.080 us; speedup vs baseline: 1.9535x; 1.3448x over previous
//
#include <hip/hip_runtime.h>
#include <cstdint>
#include <cstddef>

typedef unsigned long long ull;
typedef _Float16 f16x8 __attribute__((ext_vector_type(8)));
typedef float f32x4 __attribute__((ext_vector_type(4)));

#define N_ROWS 8192
#define SPAN   8187u   // n - k
#define MULT   1600u   // (2^32) % 8187
#define TAU_INV 10.0f
#define TOTAL_SAMP 163840u
#define INIT32 0xFFFFFFFFu

// ---------------- threefry2x32 (JAX-compatible) ----------------
__device__ __forceinline__ void tf_round(unsigned &x0, unsigned &x1, int r) {
    x0 += x1; x1 = (x1 << r) | (x1 >> (32 - r)); x1 ^= x0;
}
__device__ __forceinline__ void threefry2x32(unsigned k0, unsigned k1,
                                             unsigned c0, unsigned c1,
                                             unsigned &o0, unsigned &o1) {
    unsigned ks2 = k0 ^ k1 ^ 0x1BD11BDAu;
    unsigned x0 = c0 + k0, x1 = c1 + k1;
    tf_round(x0, x1, 13); tf_round(x0, x1, 15); tf_round(x0, x1, 26); tf_round(x0, x1, 6);
    x0 += k1;  x1 += ks2 + 1u;
    tf_round(x0, x1, 17); tf_round(x0, x1, 29); tf_round(x0, x1, 16); tf_round(x0, x1, 24);
    x0 += ks2; x1 += k0 + 2u;
    tf_round(x0, x1, 13); tf_round(x0, x1, 15); tf_round(x0, x1, 26); tf_round(x0, x1, 6);
    x0 += k0;  x1 += k1 + 3u;
    tf_round(x0, x1, 17); tf_round(x0, x1, 29); tf_round(x0, x1, 16); tf_round(x0, x1, 24);
    x0 += k1;  x1 += ks2 + 4u;
    tf_round(x0, x1, 13); tf_round(x0, x1, 15); tf_round(x0, x1, 26); tf_round(x0, x1, 6);
    x0 += ks2; x1 += k0 + 5u;
    o0 = x0; o1 = x1;
}

// ---------------- async global->LDS (16B), offset folded into pointers ----------------
// NOTE (round-4 lesson): never use the builtin's imm-offset arg; fold into pointers.
__device__ __forceinline__ void async16(void* lds, const void* g) {
    __builtin_amdgcn_global_load_lds((const __attribute__((address_space(1))) void*)g,
                                     (__attribute__((address_space(3))) void*)lds, 16, 0, 0);
}

// Stage 1KB chunk q (0..7) of a 64x64-f16 tile (row-major, 128 B/row), XOR-swizzled
// source chunk so LDS dest stays lane-linear. LDS slot (r,c) = global chunk c^(r&7).
__device__ __forceinline__ void stage_chunk(char* lds_tile, const char* gtile, int q, int lane) {
    int off16 = (q << 6) + lane;
    int r = off16 >> 3;
    int slot = off16 & 7;
    int csrc = slot ^ (r & 7);
    async16(lds_tile + (q << 10), gtile + r * 128 + (csrc << 4));
}

__device__ __forceinline__ f16x8 read_frag(const char* tile, int row, int c) {
    return *(const f16x8*)(tile + row * 128 + (((c ^ (row & 7)) << 4)));
}

// single-instruction unsigned median-of-3 (exists on gfx9-lineage incl. gfx950)
__device__ __forceinline__ unsigned umed3(unsigned a, unsigned b, unsigned c) {
    unsigned d;
    asm("v_med3_u32 %0, %1, %2, %3" : "=v"(d) : "v"(a), "v"(b), "v"(c));
    return d;
}

__device__ __forceinline__ float wave_maxf(float v) {
#pragma unroll
    for (int o = 32; o; o >>= 1) v = fmaxf(v, __shfl_xor(v, o));
    return v;
}
__device__ __forceinline__ float wave_sumf(float v) {
#pragma unroll
    for (int o = 32; o; o >>= 1) v += __shfl_xor(v, o);
    return v;
}
__device__ __forceinline__ unsigned wave_minu32(unsigned v) {
#pragma unroll
    for (int o = 32; o; o >>= 1) {
        unsigned w = (unsigned)__shfl_xor((int)v, o);
        v = (w < v) ? w : v;
    }
    return v;
}
// min over the 16-lane group (lanes sharing lq => sharing rows)
__device__ __forceinline__ unsigned group_minu32(unsigned v) {
#pragma unroll
    for (int o = 8; o; o >>= 1) {
        unsigned w = (unsigned)__shfl_xor((int)v, o);
        v = (w < v) ? w : v;
    }
    return v;
}

// ---------------- Kernel 1: norms + f16 hi/lo split ----------------
__global__ void prep_kernel(const float* __restrict__ X,
                            float2* __restrict__ nsiv,
                            char* __restrict__ Xhi,
                            char* __restrict__ Xlo) {
    int t = blockIdx.x * 256 + threadIdx.x;
    int row = t >> 3, c = t & 7;
    const float4* src = (const float4*)(X + (size_t)row * 64 + c * 8);
    float4 a = src[0], b = src[1];
    float v[8] = {a.x, a.y, a.z, a.w, b.x, b.y, b.z, b.w};
    float ss = 0.f;
#pragma unroll
    for (int j = 0; j < 8; ++j) ss = fmaf(v[j], v[j], ss);
    ss += __shfl_xor(ss, 1);
    ss += __shfl_xor(ss, 2);
    ss += __shfl_xor(ss, 4);
    f16x8 h, l;
#pragma unroll
    for (int j = 0; j < 8; ++j) {
        _Float16 hh = (_Float16)v[j];
        h[j] = hh;
        l[j] = (_Float16)(v[j] - (float)hh);
    }
    *(f16x8*)(Xhi + (size_t)row * 128 + c * 16) = h;
    *(f16x8*)(Xlo + (size_t)row * 128 + c * 16) = l;
    if (c == 0) nsiv[row] = make_float2(ss, 1.0f / (1.0f - fminf(ss, 1.0f)));
}

// ---------------- Kernel 2: MFMA gram + fused top-5 ----------------
// grid 1024 = 128 row-tiles x 8 col-chunks. 4 waves; wave w owns rows r0+16w..+15.
// v6: top-5 keys are u32 (truncated-q | col): sorted-insert = 1 v_min + 4 v_med3_u32,
// unconditional. No threshold, no per-iter shuffle reduce, no payload shadow regs.
__global__ __launch_bounds__(256, 3) void gram_topk(
        const char* __restrict__ Xhi, const char* __restrict__ Xlo,
        const float2* __restrict__ nsiv, unsigned* __restrict__ part) {
    __shared__ __align__(16) char lds[32768];

    const int t = threadIdx.x, lane = t & 63, wv = t >> 6;
    const int lx = lane & 15, lq = lane >> 4;
    const int r0 = (blockIdx.x >> 3) * 64;
    const int ch = blockIdx.x & 7;
    const int j0base = ch * 1024;

    // ---- prologue: stage A into buf0, read frags, then recycle buf0 for B ----
    const char* gAhi = Xhi + (size_t)r0 * 128;
    const char* gAlo = Xlo + (size_t)r0 * 128;
    stage_chunk(lds,        gAhi, 2 * wv, lane);
    stage_chunk(lds,        gAhi, 2 * wv + 1, lane);
    stage_chunk(lds + 8192, gAlo, 2 * wv, lane);
    stage_chunk(lds + 8192, gAlo, 2 * wv + 1, lane);
    __syncthreads();   // A staged (vmcnt drained)

    f16x8 ahi[2], alo[2];
#pragma unroll
    for (int kc = 0; kc < 2; ++kc) {
        ahi[kc] = read_frag(lds,        wv * 16 + lx, kc * 4 + lq);
        alo[kc] = read_frag(lds + 8192, wv * 16 + lx, kc * 4 + lq);
    }
    __syncthreads();   // all waves done reading A; buf0 free

    // stage B tile 0 into buf0
    stage_chunk(lds,        Xhi + (size_t)j0base * 128, 2 * wv, lane);
    stage_chunk(lds,        Xhi + (size_t)j0base * 128, 2 * wv + 1, lane);
    stage_chunk(lds + 8192, Xlo + (size_t)j0base * 128, 2 * wv, lane);
    stage_chunk(lds + 8192, Xlo + (size_t)j0base * 128, 2 * wv + 1, lane);

    // ---- precomputed addresses (lane-constant) ----
    const char* pB0 = lds + lx * 128 + ((lq       ^ (lx & 7)) << 4);
    const char* pB1 = lds + lx * 128 + (((4 + lq) ^ (lx & 7)) << 4);
    const int rA  = 16 * wv + (lane >> 3);
    const int csA = (lane & 7) ^ ((lane >> 3) & 7);
    const char* gbh = Xhi + (size_t)(j0base + 64) * 128 + rA * 128 + (csA << 4);
    const char* gbl = Xlo + (size_t)(j0base + 64) * 128 + rA * 128 + (csA << 4);
    const float2* pn = nsiv + j0base + lx;
    const int jlx = j0base + lx;

    // per-lane row stats (C/D layout: row = lq*4 + reg)
    int grow_m[4]; float rns[4];
#pragma unroll
    for (int r = 0; r < 4; ++r) {
        int gr = r0 + wv * 16 + lq * 4 + r;
        grow_m[r] = gr - jlx;          // diag when itofs + ct*16 == grow_m[r]
        rns[r] = nsiv[gr].x;
    }

    unsigned tkk[4][5];
#pragma unroll
    for (int r = 0; r < 4; ++r)
#pragma unroll
        for (int s = 0; s < 5; ++s) tkk[r][s] = INIT32;

    int itofs = 0;
    __syncthreads();   // B0 staged

#define ITER(SEL, NSEL, DO_STAGE) do {                                        \
    if (DO_STAGE) {                                                           \
        async16(lds + (NSEL) + wv * 2048,               gbh);                 \
        async16(lds + (NSEL) + wv * 2048 + 1024,        gbh + 1024);          \
        async16(lds + (NSEL) + 8192 + wv * 2048,        gbl);                 \
        async16(lds + (NSEL) + 8192 + wv * 2048 + 1024, gbl + 1024);          \
        gbh += 8192; gbl += 8192;                                             \
    }                                                                         \
    float2 cnv[4] = {pn[0], pn[16], pn[32], pn[48]};                          \
    pn += 64;                                                                 \
    f32x4 acc[4];                                                             \
    _Pragma("unroll")                                                         \
    for (int ct = 0; ct < 4; ++ct) {                                          \
        const f16x8 bh0 = *(const f16x8*)(pB0 + (SEL) + ct * 2048);           \
        const f16x8 bh1 = *(const f16x8*)(pB1 + (SEL) + ct * 2048);           \
        const f16x8 bl0 = *(const f16x8*)(pB0 + (SEL) + 8192 + ct * 2048);    \
        const f16x8 bl1 = *(const f16x8*)(pB1 + (SEL) + 8192 + ct * 2048);    \
        f32x4 a = {0.f, 0.f, 0.f, 0.f};                                       \
        a = __builtin_amdgcn_mfma_f32_16x16x32_f16(ahi[0], bh0, a, 0, 0, 0);  \
        a = __builtin_amdgcn_mfma_f32_16x16x32_f16(ahi[1], bh1, a, 0, 0, 0);  \
        a = __builtin_amdgcn_mfma_f32_16x16x32_f16(ahi[0], bl0, a, 0, 0, 0);  \
        a = __builtin_amdgcn_mfma_f32_16x16x32_f16(ahi[1], bl1, a, 0, 0, 0);  \
        a = __builtin_amdgcn_mfma_f32_16x16x32_f16(alo[0], bh0, a, 0, 0, 0);  \
        a = __builtin_amdgcn_mfma_f32_16x16x32_f16(alo[1], bh1, a, 0, 0, 0);  \
        acc[ct] = a;                                                          \
    }                                                                         \
    _Pragma("unroll")                                                         \
    for (int ct = 0; ct < 4; ++ct) {                                          \
        const float civ    = cnv[ct].y;                                       \
        const float cnsciv = cnv[ct].x * civ;                                 \
        const float m2civ  = -2.0f * civ;                                     \
        const unsigned gcol = (unsigned)(jlx + itofs + ct * 16);              \
        _Pragma("unroll")                                                     \
        for (int r = 0; r < 4; ++r) {                                         \
            float q = fmaf(acc[ct][r], m2civ, fmaf(rns[r], civ, cnsciv));     \
            q = fmaxf(q, 0.0f);                                               \
            unsigned kk = (__float_as_uint(q) & 0xFFFFE000u) | gcol;          \
            kk = (grow_m[r] == itofs + ct * 16) ? INIT32 : kk;                \
            tkk[r][4] = umed3(tkk[r][3], tkk[r][4], kk);                      \
            tkk[r][3] = umed3(tkk[r][2], tkk[r][3], kk);                      \
            tkk[r][2] = umed3(tkk[r][1], tkk[r][2], kk);                      \
            tkk[r][1] = umed3(tkk[r][0], tkk[r][1], kk);                      \
            tkk[r][0] = (kk < tkk[r][0]) ? kk : tkk[r][0];                    \
        }                                                                     \
    }                                                                         \
    itofs += 64;                                                              \
    __syncthreads();                                                          \
} while (0)

#pragma unroll 1
    for (int ip = 0; ip < 8; ++ip) {
        ITER(0, 16384, true);       // it = 2*ip   : read buf0, stage buf1
        ITER(16384, 0, ip < 7);     // it = 2*ip+1 : read buf1, stage buf0
    }
#undef ITER

    // ---- in-register merge: 16 lanes x sorted-5 -> row top-5, 5 rounds of group-min ----
    // keys unique across lanes (col mod 16 == lx), so exactly the winner advances.
#pragma unroll
    for (int r = 0; r < 4; ++r) {
        unsigned t5r[5];
#pragma unroll
        for (int s = 0; s < 5; ++s) t5r[s] = tkk[r][s];
        unsigned out = INIT32;
        unsigned h = t5r[0];
#pragma unroll
        for (int s = 0; s < 5; ++s) {
            unsigned m = group_minu32(h);
            if (lx == s) out = m;
            if (h == m) {
                t5r[0] = t5r[1]; t5r[1] = t5r[2]; t5r[2] = t5r[3];
                t5r[3] = t5r[4]; t5r[4] = INIT32;
                h = t5r[0];
            }
        }
        if (lx < 5) part[(size_t)(grow_m[r] + jlx) * 40 + (size_t)ch * 5 + lx] = out;
    }
}

// ---------------- Kernel 3: finalize, 4 rows/block (wave per row), shuffle-parallel ----------------
__global__ __launch_bounds__(256) void finalize_kernel(
        const float* __restrict__ X, const float2* __restrict__ nsiv,
        const unsigned* __restrict__ part, float* __restrict__ rowloss) {
    const int t = threadIdx.x, lane = t & 63, wv = t >> 6;
    const int row = blockIdx.x * 4 + wv;

    // merge chunk top-5s (40 u32 keys) -> global top-5 via 5 wave-min passes
    unsigned key = (lane < 40) ? part[(size_t)row * 40 + lane] : INIT32;
    unsigned b[5];
#pragma unroll
    for (int s = 0; s < 5; ++s) {
        unsigned m = wave_minu32(key);
        b[s] = m;
        if (key == m) key = INIT32;   // cols embedded -> keys unique -> unique min
    }

    int pcol[5], ids[5];
#pragma unroll
    for (int s = 0; s < 5; ++s) { pcol[s] = (int)(b[s] & 8191u); ids[s] = pcol[s]; }
    // sort excluded ids ascending (tiny; every lane duplicates)
    for (int i = 0; i < 4; ++i)
        for (int j = 0; j < 4 - i; ++j)
            if (ids[j] > ids[j + 1]) { int tmp = ids[j]; ids[j] = ids[j + 1]; ids[j + 1] = tmp; }

    // column for this lane: lanes 0..19 = sampled negatives, 20..24 = positives
    int col = row;
    if (lane < 20) {
        unsigned m0 = (unsigned)(row * 20 + lane);
        unsigned hi, lo;
        threefry2x32(0u, 42u, m0, m0 + TOTAL_SAMP, hi, lo);
        unsigned samp = ((hi % SPAN) * MULT + (lo % SPAN)) % SPAN;
        int c = (int)samp;
#pragma unroll
        for (int s = 0; s < 5; ++s) c += (ids[s] <= c) ? 1 : 0;
        col = c;
    } else if (lane < 25) {
        col = pcol[lane - 20];
    }

    // exact fp32 Poincare distance term  -dist/tau  (diagonal -> -inf)
    float term = -INFINITY;
    if (lane < 25 && col != row) {
        const float4* xr = (const float4*)(X + (size_t)row * 64);
        const float4* xc = (const float4*)(X + (size_t)col * 64);
        float dot = 0.f;
#pragma unroll
        for (int k = 0; k < 16; ++k) {
            float4 a = xr[k];
            float4 c = xc[k];
            dot = fmaf(a.x, c.x, dot);
            dot = fmaf(a.y, c.y, dot);
            dot = fmaf(a.z, c.z, dot);
            dot = fmaf(a.w, c.w, dot);
        }
        float nsi = nsiv[row].x, nsj = nsiv[col].x;
        float d2  = fmaxf(nsi + nsj - 2.f * dot, 0.f);
        float ci  = 1.f - fminf(nsi, 1.f);
        float cj  = 1.f - fminf(nsj, 1.f);
        float den = fmaxf(ci * cj, 1e-9f);
        float z   = fmaxf(1.f + 2.f * d2 / den, 1.f);
        term = -acoshf(z) * TAU_INV;
    }

    // two masked LSEs across the wave
    float negt = (lane < 20) ? term : -INFINITY;
    float post = (lane >= 20 && lane < 25) ? term : -INFINITY;

    float nm = wave_maxf(negt);
    float ne = (lane < 20 && negt != -INFINITY) ? expf(negt - nm) : 0.f;
    float neg = nm + logf(wave_sumf(ne));

    float pm = wave_maxf(post);
    float pe = (lane >= 20 && lane < 25) ? expf(post - pm) : 0.f;
    float pos = pm + logf(wave_sumf(pe));

    if (lane == 0) rowloss[row] = neg - pos;
}

// ---------------- Kernel 4: deterministic tree sum ----------------
__global__ void reduce_kernel(const float* __restrict__ rl, float* __restrict__ out) {
    const int t = threadIdx.x;
    float s = 0.f;
#pragma unroll
    for (int i = 0; i < 32; ++i) s += rl[t + 256 * i];
#pragma unroll
    for (int o = 32; o; o >>= 1) s += __shfl_xor(s, o);
    __shared__ float ws4[4];
    if ((t & 63) == 0) ws4[t >> 6] = s;
    __syncthreads();
    if (t == 0) out[0] = (ws4[0] + ws4[1] + ws4[2] + ws4[3]) * (1.0f / 8192.0f);
}

// ---------------- launch ----------------
extern "C" void kernel_launch(void* const* d_in, const int* in_sizes, int n_in,
                              void* d_out, int out_size, void* d_ws, size_t ws_size,
                              hipStream_t stream) {
    (void)in_sizes; (void)n_in; (void)out_size; (void)ws_size;
    const float* X = (const float*)d_in[0];
    float* out = (float*)d_out;

    float2*   nsiv    = (float2*)d_ws;                                  // 64 KB
    char*     Xhi     = (char*)d_ws + 65536;                            // 1 MB
    char*     Xlo     = (char*)d_ws + 65536 + 1048576;                  // 1 MB
    unsigned* part    = (unsigned*)((char*)d_ws + 65536 + 2097152);     // 1.25 MB (8192*40*4)
    float*    rowloss = (float*)((char*)d_ws + 65536 + 2097152 + 1310720); // 32 KB

    prep_kernel<<<256, 256, 0, stream>>>(X, nsiv, Xhi, Xlo);
    gram_topk<<<1024, 256, 0, stream>>>(Xhi, Xlo, nsiv, part);
    finalize_kernel<<<2048, 256, 0, stream>>>(X, nsiv, part, rowloss);
    reduce_kernel<<<1, 256, 0, stream>>>(rowloss, out);
}